// Round 10
// baseline (706.399 us; speedup 1.0000x reference)
//
#include <hip/hip_runtime.h>

typedef unsigned short u16;
typedef unsigned int   u32;
typedef __bf16 bf16x8 __attribute__((ext_vector_type(8)));  // MFMA A/B (4 VGPRs)
typedef float  f32x4  __attribute__((ext_vector_type(4)));  // MFMA C/D

#define BH    16
#define NSEQ  4096
#define DIM   64
#define BM    64            // Q rows per block (4 waves x 16)
#define BN    64            // K rows per tile
#define LDP   72            // K LDS row stride (u16): b128 ops uniform 8/bank (min)
#define LDPP  68            // P-strip row stride (u16): writes 2/bank, b64 reads 4/bank
#define KSZ   (BN * LDP)    // one K buffer, u16 units
#define NT    (NSEQ / BN)   // 64 K-tiles
#define QTILES (NSEQ / BM)  // 64

__device__ __forceinline__ float bf2f(u16 u) {
    union { u32 i; float f; } v; v.i = ((u32)u) << 16; return v.f;
}
__device__ __forceinline__ u16 f2bf(float f) {          // true RNE
    union { float f; u32 i; } v; v.f = f;
    u32 r = v.i + 0x7fffu + ((v.i >> 16) & 1u);
    return (u16)(r >> 16);
}
__device__ __forceinline__ u16 f2bf_fast(float f) {     // round-half-up, 2 VALU ops
    union { float f; u32 i; } v; v.f = f;
    return (u16)((v.i + 0x8000u) >> 16);
}
#if __has_builtin(__builtin_amdgcn_exp2f)
__device__ __forceinline__ float exp2_raw(float x) { return __builtin_amdgcn_exp2f(x); }
#else
__device__ __forceinline__ float exp2_raw(float x) {
    float r; asm("v_exp_f32 %0, %1" : "=v"(r) : "v"(x)); return r;
}
#endif

// ---------------------------------------------------------------------------
// prep: L2-normalize rows -> xn (bf16); transpose raw values -> xT (bf16)
// isf=1: src fp32; isf=0: src bf16. grid BH*16 x 256 (1 row/thread)
// tile stride 72 u16 (144B, 16B-aligned rows) -> staging writes are b128.
// ---------------------------------------------------------------------------
__global__ __launch_bounds__(256) void ContentGCN_5059471475267_prep(
    const void* __restrict__ src, int isf,
    u16* __restrict__ xn, u16* __restrict__ xT)
{
    __shared__ u16 tile[256 * 72];
    int bh = blockIdx.x >> 4, nt = blockIdx.x & 15, tid = threadIdx.x;
    size_t base = ((size_t)bh * NSEQ + nt * 256 + tid) * DIM;

    float v[64];
    if (isf) {
        const float4* g = (const float4*)((const float*)src + base);
#pragma unroll
        for (int i = 0; i < 16; i++) {
            float4 t4 = g[i];
            v[4*i] = t4.x; v[4*i+1] = t4.y; v[4*i+2] = t4.z; v[4*i+3] = t4.w;
        }
    } else {
        alignas(16) u16 tmp[64];
        const uint4* g = (const uint4*)((const u16*)src + base);
#pragma unroll
        for (int i = 0; i < 8; i++) ((uint4*)tmp)[i] = g[i];
#pragma unroll
        for (int d = 0; d < 64; d++) v[d] = bf2f(tmp[d]);
    }

    float ss = 0.f;
#pragma unroll
    for (int d = 0; d < 64; d++) ss += v[d] * v[d];
    float n = sqrtf(ss);
    if (n < 1e-12f) n = 1e-12f;            // F.normalize eps
    float inv = 1.0f / n;

    alignas(16) u16 nb[64], rb[64];
#pragma unroll
    for (int d = 0; d < 64; d++) { nb[d] = f2bf(v[d] * inv); rb[d] = f2bf(v[d]); }
    uint4* gn = (uint4*)(xn + base);
#pragma unroll
    for (int i = 0; i < 8; i++) gn[i] = ((uint4*)nb)[i];

    uint4* trow = (uint4*)&tile[tid * 72];
#pragma unroll
    for (int i = 0; i < 8; i++) trow[i] = ((uint4*)rb)[i];
    __syncthreads();

    int d = tid & 63, ch = tid >> 6;
    alignas(16) u16 ob[64];
#pragma unroll
    for (int nn = 0; nn < 64; nn++) ob[nn] = tile[(ch * 64 + nn) * 72 + d];
    uint4* gt = (uint4*)(xT + ((size_t)bh * DIM + d) * NSEQ + (size_t)nt * 256 + ch * 64);
#pragma unroll
    for (int i = 0; i < 8; i++) gt[i] = ((uint4*)ob)[i];
}

// ---------------------------------------------------------------------------
// attn: MFMA flash attention. K double-buffered in LDS with ONE relaxed
// barrier per iter (lgkmcnt-only: prefetches stay in flight). V fragments
// loaded per-lane directly from global (L2-resident, coalesced), reloaded
// after last use. Fixed-max softmax (diag cosine == 1). 27.1 KB LDS.
// ---------------------------------------------------------------------------
__global__ __launch_bounds__(256) void ContentGCN_5059471475267_attn(
    const u16* __restrict__ xn, const u16* __restrict__ xT,
    const void* __restrict__ res, int res_isf,
    const float* __restrict__ Wt, const float* __restrict__ alphap,
    void* __restrict__ outp, int out_isf)
{
    __shared__ u16 sK[2 * KSZ];         // double-buffered K; W at epilogue
    __shared__ u16 sP[4 * 16 * LDPP];   // wave-private P strips

    int tid  = threadIdx.x;
    int wave = tid >> 6, lane = tid & 63;
    int quad = lane >> 4, l16 = lane & 15;
    int bh   = blockIdx.x >> 6;
    int qt   = blockIdx.x & 63;

    float scale = 1.4426950408889634f / fmaxf(alphap[0], 0.01f);  // exp2 domain

    // Q fragments (A-layout: m=l16, k=quad*8+j)
    int qrow = qt * BM + wave * 16 + l16;
    size_t qbase = ((size_t)bh * NSEQ + qrow) * DIM;
    bf16x8 aQ0 = *(const bf16x8*)(xn + qbase + quad * 8);
    bf16x8 aQ1 = *(const bf16x8*)(xn + qbase + 32 + quad * 8);

    const f32x4 fzero = {0.f, 0.f, 0.f, 0.f};
    f32x4 O[4];
#pragma unroll
    for (int t = 0; t < 4; t++) O[t] = fzero;
    float l_r[4] = {0.f, 0.f, 0.f, 0.f};

    u16* sPw = sP + wave * (16 * LDPP);
    int srow = tid >> 2, scol = (tid & 3) * 16;   // K staging: 16 u16/thread

    // K staging regs (2-iter-ahead pipeline)
    const u16* pk = xn + ((size_t)bh * NSEQ + srow) * DIM + scol;
    uint4 ck0 = ((const uint4*)pk)[0], ck1 = ((const uint4*)pk)[1];
    pk += (size_t)BN * DIM;

    // V fragments direct from global: rows l16+16t of xT, cols quad*8 (+32)
    const u16* pv0 = xT + ((size_t)bh * DIM + l16) * NSEQ + quad * 8;
    const u16* pv1 = pv0 + (size_t)16 * NSEQ;
    const u16* pv2 = pv0 + (size_t)32 * NSEQ;
    const u16* pv3 = pv0 + (size_t)48 * NSEQ;
    bf16x8 vf[8];
    vf[0] = *(const bf16x8*)pv0; vf[1] = *(const bf16x8*)(pv0 + 32);
    vf[2] = *(const bf16x8*)pv1; vf[3] = *(const bf16x8*)(pv1 + 32);
    vf[4] = *(const bf16x8*)pv2; vf[5] = *(const bf16x8*)(pv2 + 32);
    vf[6] = *(const bf16x8*)pv3; vf[7] = *(const bf16x8*)(pv3 + 32);
    pv0 += BN; pv1 += BN; pv2 += BN; pv3 += BN;

    // stage K0, full sync once, prefetch K1
    *(uint4*)&sK[srow * LDP + scol]     = ck0;
    *(uint4*)&sK[srow * LDP + scol + 8] = ck1;
    __syncthreads();
    ck0 = ((const uint4*)pk)[0]; ck1 = ((const uint4*)pk)[1];
    pk += (size_t)BN * DIM;

    for (int kt = 0; kt < NT; kt++) {
        const u16* kb = sK + (kt & 1) * KSZ;

        // S = Qn @ Kn^T (16 rows x 64 cols per wave)
        f32x4 S[4];
#pragma unroll
        for (int t = 0; t < 4; t++) {
            bf16x8 b0 = *(const bf16x8*)&kb[(l16 + 16 * t) * LDP + quad * 8];
            bf16x8 b1 = *(const bf16x8*)&kb[(l16 + 16 * t) * LDP + 32 + quad * 8];
            f32x4 acc = fzero;
            acc = __builtin_amdgcn_mfma_f32_16x16x32_bf16(aQ0, b0, acc, 0, 0, 0);
            acc = __builtin_amdgcn_mfma_f32_16x16x32_bf16(aQ1, b1, acc, 0, 0, 0);
            S[t] = acc;
        }

        // stage K(kt+1) into the OTHER buffer (safe: last reads of that
        // buffer finished before the previous barrier)
        if (kt + 1 < NT) {
            u16* kn = sK + ((kt + 1) & 1) * KSZ;
            *(uint4*)&kn[srow * LDP + scol]     = ck0;
            *(uint4*)&kn[srow * LDP + scol + 8] = ck1;
        }
        // relaxed barrier: drain LDS only; vmcnt prefetches stay in flight
        asm volatile("s_waitcnt lgkmcnt(0)\n\ts_barrier" ::: "memory");
        if (kt + 2 < NT) {
            ck0 = ((const uint4*)pk)[0]; ck1 = ((const uint4*)pk)[1];
            pk += (size_t)BN * DIM;
        }

        // fixed-max softmax: p = exp2(s*scale - scale)
#pragma unroll
        for (int r = 0; r < 4; r++) {
            float ps = 0.f;
#pragma unroll
            for (int t = 0; t < 4; t++) {
                float p = exp2_raw(fmaf(S[t][r], scale, -scale));
                ps += p;
                sPw[(quad * 4 + r) * LDPP + l16 + 16 * t] = f2bf_fast(p);
            }
            l_r[r] += ps;
        }

        // PV: A = P (wave-private LDS round-trip), B = V frags (registers)
        union { uint2 u[2]; bf16x8 v; } pA0, pA1;
        pA0.u[0] = *(const uint2*)&sPw[l16 * LDPP + quad * 8];
        pA0.u[1] = *(const uint2*)&sPw[l16 * LDPP + quad * 8 + 4];
        pA1.u[0] = *(const uint2*)&sPw[l16 * LDPP + 32 + quad * 8];
        pA1.u[1] = *(const uint2*)&sPw[l16 * LDPP + 32 + quad * 8 + 4];
#pragma unroll
        for (int t = 0; t < 4; t++) {
            O[t] = __builtin_amdgcn_mfma_f32_16x16x32_bf16(pA0.v, vf[2*t],   O[t], 0, 0, 0);
            O[t] = __builtin_amdgcn_mfma_f32_16x16x32_bf16(pA1.v, vf[2*t+1], O[t], 0, 0, 0);
        }

        // reload V frags for next tile (off critical path; used next PV)
        if (kt + 1 < NT) {
            vf[0] = *(const bf16x8*)pv0; vf[1] = *(const bf16x8*)(pv0 + 32);
            vf[2] = *(const bf16x8*)pv1; vf[3] = *(const bf16x8*)(pv1 + 32);
            vf[4] = *(const bf16x8*)pv2; vf[5] = *(const bf16x8*)(pv2 + 32);
            vf[6] = *(const bf16x8*)pv3; vf[7] = *(const bf16x8*)(pv3 + 32);
            pv0 += BN; pv1 += BN; pv2 += BN; pv3 += BN;
        }
    }

    // deferred l reduction + av -> sPw (bf16)
#pragma unroll
    for (int r = 0; r < 4; r++) {
        float l = l_r[r];
        l += __shfl_xor(l, 1);
        l += __shfl_xor(l, 2);
        l += __shfl_xor(l, 4);
        l += __shfl_xor(l, 8);
        float invl = 1.0f / l;
#pragma unroll
        for (int t = 0; t < 4; t++)
            sPw[(quad * 4 + r) * LDPP + l16 + 16 * t] = f2bf_fast(O[t][r] * invl);
    }
    union { uint2 u[2]; bf16x8 v; } aA0, aA1;
    aA0.u[0] = *(const uint2*)&sPw[l16 * LDPP + quad * 8];
    aA0.u[1] = *(const uint2*)&sPw[l16 * LDPP + quad * 8 + 4];
    aA1.u[0] = *(const uint2*)&sPw[l16 * LDPP + 32 + quad * 8];
    aA1.u[1] = *(const uint2*)&sPw[l16 * LDPP + 32 + quad * 8 + 4];

    // stage W (fp32 -> bf16) into sK buf0 (dead); full sync before reads
    {
        int r = tid >> 2, c0 = (tid & 3) * 16;
        alignas(16) u16 wb[16];
        const float4* gw = (const float4*)(Wt + r * DIM + c0);
#pragma unroll
        for (int i = 0; i < 4; i++) {
            float4 t4 = gw[i];
            wb[4*i]   = f2bf(t4.x); wb[4*i+1] = f2bf(t4.y);
            wb[4*i+2] = f2bf(t4.z); wb[4*i+3] = f2bf(t4.w);
        }
        *(uint4*)&sK[r * LDP + c0]     = ((uint4*)wb)[0];
        *(uint4*)&sK[r * LDP + c0 + 8] = ((uint4*)wb)[1];
    }
    __syncthreads();

    f32x4 R[4];
#pragma unroll
    for (int t = 0; t < 4; t++) {
        bf16x8 b0 = *(const bf16x8*)&sK[(l16 + 16 * t) * LDP + quad * 8];
        bf16x8 b1 = *(const bf16x8*)&sK[(l16 + 16 * t) * LDP + 32 + quad * 8];
        f32x4 acc = fzero;
        acc = __builtin_amdgcn_mfma_f32_16x16x32_bf16(aA0.v, b0, acc, 0, 0, 0);
        acc = __builtin_amdgcn_mfma_f32_16x16x32_bf16(aA1.v, b1, acc, 0, 0, 0);
        R[t] = acc;
    }
#pragma unroll
    for (int t = 0; t < 4; t++) {
#pragma unroll
        for (int r = 0; r < 4; r++) {
            int row = qt * BM + wave * 16 + quad * 4 + r;
            int col = l16 + 16 * t;
            size_t idx = ((size_t)bh * NSEQ + row) * DIM + col;
            float rv = res_isf ? ((const float*)res)[idx] : bf2f(((const u16*)res)[idx]);
            float v = R[t][r] + rv;
            v = (v < 0.f) ? 0.f : v;       // NaN-transparent relu
            if (out_isf) ((float*)outp)[idx] = v;
            else         ((u16*)outp)[idx]  = f2bf(v);
        }
    }
}

extern "C" void kernel_launch(void* const* d_in, const int* in_sizes, int n_in,
                              void* d_out, int out_size, void* d_ws, size_t ws_size,
                              hipStream_t stream) {
    const float* x  = (const float*)d_in[0];
    const float* W1 = (const float*)d_in[1];
    const float* W2 = (const float*)d_in[2];
    const float* a1 = (const float*)d_in[3];
    const float* a2 = (const float*)d_in[4];
    float* outp = (float*)d_out;

    size_t elems = (size_t)BH * NSEQ * DIM;        // 4,194,304
    u16* xn = (u16*)d_ws;                          // 8.39 MB
    u16* xT = xn + elems;                          // 8.39 MB
    u16* y1 = xT + elems;                          // 8.39 MB (layer-1 out, bf16)

    dim3 pgrid(BH * 16),     pblk(256);
    dim3 agrid(BH * QTILES), ablk(256);

    // layer 1: x (fp32) -> y1 (bf16)
    ContentGCN_5059471475267_prep<<<pgrid, pblk, 0, stream>>>(x, 1, xn, xT);
    ContentGCN_5059471475267_attn<<<agrid, ablk, 0, stream>>>(xn, xT, x, 1, W1, a1, y1, 0);
    // layer 2: y1 (bf16) -> d_out (fp32)
    ContentGCN_5059471475267_prep<<<pgrid, pblk, 0, stream>>>(y1, 0, xn, xT);
    ContentGCN_5059471475267_attn<<<agrid, ablk, 0, stream>>>(xn, xT, y1, 0, W2, a2, outp, 1);
}

// Round 11
// 371.791 us; speedup vs baseline: 1.9000x; 1.9000x over previous
//
#include <hip/hip_runtime.h>

typedef unsigned short u16;
typedef unsigned int   u32;
typedef __bf16 bf16x8 __attribute__((ext_vector_type(8)));  // MFMA A/B (4 VGPRs)
typedef float  f32x4  __attribute__((ext_vector_type(4)));  // MFMA C/D

#define BH    16
#define NSEQ  4096
#define DIM   64
#define BM    64            // Q rows per block (4 waves x 16)
#define BN    64            // K rows per tile
#define LDP   72            // K/V LDS row stride (u16): b128 ops uniform 8/bank (min)
#define LDPP  68            // P-strip row stride (u16): writes 2/bank, b64 reads 4/bank
#define KSZ   (BN * LDP)    // one K/V buffer, u16 units (9216 B)
#define NT    (NSEQ / BN)   // 64 K-tiles
#define QTILES (NSEQ / BM)  // 64

__device__ __forceinline__ float bf2f(u16 u) {
    union { u32 i; float f; } v; v.i = ((u32)u) << 16; return v.f;
}
__device__ __forceinline__ u16 f2bf(float f) {          // true RNE
    union { float f; u32 i; } v; v.f = f;
    u32 r = v.i + 0x7fffu + ((v.i >> 16) & 1u);
    return (u16)(r >> 16);
}
__device__ __forceinline__ u16 f2bf_fast(float f) {     // round-half-up, 2 VALU ops
    union { float f; u32 i; } v; v.f = f;
    return (u16)((v.i + 0x8000u) >> 16);
}
#if __has_builtin(__builtin_amdgcn_exp2f)
__device__ __forceinline__ float exp2_raw(float x) { return __builtin_amdgcn_exp2f(x); }
#else
__device__ __forceinline__ float exp2_raw(float x) {
    float r; asm("v_exp_f32 %0, %1" : "=v"(r) : "v"(x)); return r;
}
#endif

// ---------------------------------------------------------------------------
// prep: L2-normalize rows -> xn (bf16); transpose raw values -> xT (bf16)
// isf=1: src fp32; isf=0: src bf16. grid BH*16 x 256 (1 row/thread)
// ---------------------------------------------------------------------------
__global__ __launch_bounds__(256) void ContentGCN_5059471475267_prep(
    const void* __restrict__ src, int isf,
    u16* __restrict__ xn, u16* __restrict__ xT)
{
    __shared__ u16 tile[256 * 72];
    int bh = blockIdx.x >> 4, nt = blockIdx.x & 15, tid = threadIdx.x;
    size_t base = ((size_t)bh * NSEQ + nt * 256 + tid) * DIM;

    float v[64];
    if (isf) {
        const float4* g = (const float4*)((const float*)src + base);
#pragma unroll
        for (int i = 0; i < 16; i++) {
            float4 t4 = g[i];
            v[4*i] = t4.x; v[4*i+1] = t4.y; v[4*i+2] = t4.z; v[4*i+3] = t4.w;
        }
    } else {
        alignas(16) u16 tmp[64];
        const uint4* g = (const uint4*)((const u16*)src + base);
#pragma unroll
        for (int i = 0; i < 8; i++) ((uint4*)tmp)[i] = g[i];
#pragma unroll
        for (int d = 0; d < 64; d++) v[d] = bf2f(tmp[d]);
    }

    float ss = 0.f;
#pragma unroll
    for (int d = 0; d < 64; d++) ss += v[d] * v[d];
    float n = sqrtf(ss);
    if (n < 1e-12f) n = 1e-12f;            // F.normalize eps
    float inv = 1.0f / n;

    alignas(16) u16 nb[64], rb[64];
#pragma unroll
    for (int d = 0; d < 64; d++) { nb[d] = f2bf(v[d] * inv); rb[d] = f2bf(v[d]); }
    uint4* gn = (uint4*)(xn + base);
#pragma unroll
    for (int i = 0; i < 8; i++) gn[i] = ((uint4*)nb)[i];

    uint4* trow = (uint4*)&tile[tid * 72];
#pragma unroll
    for (int i = 0; i < 8; i++) trow[i] = ((uint4*)rb)[i];
    __syncthreads();

    int d = tid & 63, ch = tid >> 6;
    alignas(16) u16 ob[64];
#pragma unroll
    for (int nn = 0; nn < 64; nn++) ob[nn] = tile[(ch * 64 + nn) * 72 + d];
    uint4* gt = (uint4*)(xT + ((size_t)bh * DIM + d) * NSEQ + (size_t)nt * 256 + ch * 64);
#pragma unroll
    for (int i = 0; i < 8; i++) gt[i] = ((uint4*)ob)[i];
}

// ---------------------------------------------------------------------------
// attn: MFMA flash attention. K AND V double-buffered in LDS -> ONE
// __syncthreads per iter, placed at iter END so the prefetch global loads
// (issued before the compute phase) land before the barrier's vmcnt drain.
// Fixed-max softmax (diag cosine == 1). 45.5 KB LDS (3 blocks/CU).
// ---------------------------------------------------------------------------
__global__ __launch_bounds__(256) void ContentGCN_5059471475267_attn(
    const u16* __restrict__ xn, const u16* __restrict__ xT,
    const void* __restrict__ res, int res_isf,
    const float* __restrict__ Wt, const float* __restrict__ alphap,
    void* __restrict__ outp, int out_isf)
{
    __shared__ u16 sK[2 * KSZ];         // double-buffered K; W at epilogue
    __shared__ u16 sV[2 * KSZ];         // double-buffered V^T: [d][k]
    __shared__ u16 sP[4 * 16 * LDPP];   // wave-private P strips

    int tid  = threadIdx.x;
    int wave = tid >> 6, lane = tid & 63;
    int quad = lane >> 4, l16 = lane & 15;
    int bh   = blockIdx.x >> 6;
    int qt   = blockIdx.x & 63;

    float scale = 1.4426950408889634f / fmaxf(alphap[0], 0.01f);  // exp2 domain

    // Q fragments (A-layout: m=l16, k=quad*8+j)
    int qrow = qt * BM + wave * 16 + l16;
    size_t qbase = ((size_t)bh * NSEQ + qrow) * DIM;
    bf16x8 aQ0 = *(const bf16x8*)(xn + qbase + quad * 8);
    bf16x8 aQ1 = *(const bf16x8*)(xn + qbase + 32 + quad * 8);

    const f32x4 fzero = {0.f, 0.f, 0.f, 0.f};
    f32x4 O[4];
#pragma unroll
    for (int t = 0; t < 4; t++) O[t] = fzero;
    float l_r[4] = {0.f, 0.f, 0.f, 0.f};

    u16* sPw = sP + wave * (16 * LDPP);
    int srow = tid >> 2, scol = (tid & 3) * 16;   // staging: 16 u16/thread each for K,V

    // staging pointers, constant bumps
    const u16* pk = xn + ((size_t)bh * NSEQ + srow) * DIM + scol;   // += BN*DIM
    const u16* pv = xT + ((size_t)bh * DIM + srow) * NSEQ + scol;   // += BN

    // tile 0: load, stage into buf0, sync, then prefetch tile 1
    uint4 ck0 = ((const uint4*)pk)[0], ck1 = ((const uint4*)pk)[1];
    uint4 cv0 = ((const uint4*)pv)[0], cv1 = ((const uint4*)pv)[1];
    pk += (size_t)BN * DIM; pv += BN;
    *(uint4*)&sK[srow * LDP + scol]     = ck0;
    *(uint4*)&sK[srow * LDP + scol + 8] = ck1;
    *(uint4*)&sV[srow * LDP + scol]     = cv0;
    *(uint4*)&sV[srow * LDP + scol + 8] = cv1;
    __syncthreads();
    ck0 = ((const uint4*)pk)[0]; ck1 = ((const uint4*)pk)[1];
    cv0 = ((const uint4*)pv)[0]; cv1 = ((const uint4*)pv)[1];
    pk += (size_t)BN * DIM; pv += BN;

    for (int kt = 0; kt < NT; kt++) {
        const u16* kb = sK + (kt & 1) * KSZ;
        const u16* vb = sV + (kt & 1) * KSZ;

        // write tile kt+1 (regs, loaded last iter) into the other buffers;
        // safe: those buffers' last readers finished before the previous barrier
        if (kt + 1 < NT) {
            u16* kn = sK + ((kt + 1) & 1) * KSZ;
            u16* vn = sV + ((kt + 1) & 1) * KSZ;
            *(uint4*)&kn[srow * LDP + scol]     = ck0;
            *(uint4*)&kn[srow * LDP + scol + 8] = ck1;
            *(uint4*)&vn[srow * LDP + scol]     = cv0;
            *(uint4*)&vn[srow * LDP + scol + 8] = cv1;
        }
        // issue prefetch of tile kt+2 NOW: lands during the compute phase,
        // so the end-of-iter barrier's vmcnt drain doesn't stall
        if (kt + 2 < NT) {
            ck0 = ((const uint4*)pk)[0]; ck1 = ((const uint4*)pk)[1];
            cv0 = ((const uint4*)pv)[0]; cv1 = ((const uint4*)pv)[1];
            pk += (size_t)BN * DIM; pv += BN;
        }

        // S = Qn @ Kn^T (16 rows x 64 cols per wave)
        f32x4 S[4];
#pragma unroll
        for (int t = 0; t < 4; t++) {
            bf16x8 b0 = *(const bf16x8*)&kb[(l16 + 16 * t) * LDP + quad * 8];
            bf16x8 b1 = *(const bf16x8*)&kb[(l16 + 16 * t) * LDP + 32 + quad * 8];
            f32x4 acc = fzero;
            acc = __builtin_amdgcn_mfma_f32_16x16x32_bf16(aQ0, b0, acc, 0, 0, 0);
            acc = __builtin_amdgcn_mfma_f32_16x16x32_bf16(aQ1, b1, acc, 0, 0, 0);
            S[t] = acc;
        }

        // fixed-max softmax: p = exp2(s*scale - scale)
#pragma unroll
        for (int r = 0; r < 4; r++) {
            float ps = 0.f;
#pragma unroll
            for (int t = 0; t < 4; t++) {
                float p = exp2_raw(fmaf(S[t][r], scale, -scale));
                ps += p;
                sPw[(quad * 4 + r) * LDPP + l16 + 16 * t] = f2bf_fast(p);
            }
            l_r[r] += ps;
        }

        // PV: A = P (wave-private LDS round-trip), B = V^T rows from LDS
        union { uint2 u[2]; bf16x8 v; } pA0, pA1;
        pA0.u[0] = *(const uint2*)&sPw[l16 * LDPP + quad * 8];
        pA0.u[1] = *(const uint2*)&sPw[l16 * LDPP + quad * 8 + 4];
        pA1.u[0] = *(const uint2*)&sPw[l16 * LDPP + 32 + quad * 8];
        pA1.u[1] = *(const uint2*)&sPw[l16 * LDPP + 32 + quad * 8 + 4];
#pragma unroll
        for (int t = 0; t < 4; t++) {
            bf16x8 b0 = *(const bf16x8*)&vb[(l16 + 16 * t) * LDP + quad * 8];
            bf16x8 b1 = *(const bf16x8*)&vb[(l16 + 16 * t) * LDP + 32 + quad * 8];
            O[t] = __builtin_amdgcn_mfma_f32_16x16x32_bf16(pA0.v, b0, O[t], 0, 0, 0);
            O[t] = __builtin_amdgcn_mfma_f32_16x16x32_bf16(pA1.v, b1, O[t], 0, 0, 0);
        }

        __syncthreads();   // single barrier: publishes tile kt+1, closes reads of kt
    }

    // deferred l reduction + av -> sPw (bf16)
#pragma unroll
    for (int r = 0; r < 4; r++) {
        float l = l_r[r];
        l += __shfl_xor(l, 1);
        l += __shfl_xor(l, 2);
        l += __shfl_xor(l, 4);
        l += __shfl_xor(l, 8);
        float invl = 1.0f / l;
#pragma unroll
        for (int t = 0; t < 4; t++)
            sPw[(quad * 4 + r) * LDPP + l16 + 16 * t] = f2bf_fast(O[t][r] * invl);
    }
    union { uint2 u[2]; bf16x8 v; } aA0, aA1;
    aA0.u[0] = *(const uint2*)&sPw[l16 * LDPP + quad * 8];
    aA0.u[1] = *(const uint2*)&sPw[l16 * LDPP + quad * 8 + 4];
    aA1.u[0] = *(const uint2*)&sPw[l16 * LDPP + 32 + quad * 8];
    aA1.u[1] = *(const uint2*)&sPw[l16 * LDPP + 32 + quad * 8 + 4];

    // stage W (fp32 -> bf16) into sK buf0 (dead after final barrier)
    {
        int r = tid >> 2, c0 = (tid & 3) * 16;
        alignas(16) u16 wb[16];
        const float4* gw = (const float4*)(Wt + r * DIM + c0);
#pragma unroll
        for (int i = 0; i < 4; i++) {
            float4 t4 = gw[i];
            wb[4*i]   = f2bf(t4.x); wb[4*i+1] = f2bf(t4.y);
            wb[4*i+2] = f2bf(t4.z); wb[4*i+3] = f2bf(t4.w);
        }
        *(uint4*)&sK[r * LDP + c0]     = ((uint4*)wb)[0];
        *(uint4*)&sK[r * LDP + c0 + 8] = ((uint4*)wb)[1];
    }
    __syncthreads();

    f32x4 R[4];
#pragma unroll
    for (int t = 0; t < 4; t++) {
        bf16x8 b0 = *(const bf16x8*)&sK[(l16 + 16 * t) * LDP + quad * 8];
        bf16x8 b1 = *(const bf16x8*)&sK[(l16 + 16 * t) * LDP + 32 + quad * 8];
        f32x4 acc = fzero;
        acc = __builtin_amdgcn_mfma_f32_16x16x32_bf16(aA0.v, b0, acc, 0, 0, 0);
        acc = __builtin_amdgcn_mfma_f32_16x16x32_bf16(aA1.v, b1, acc, 0, 0, 0);
        R[t] = acc;
    }
#pragma unroll
    for (int t = 0; t < 4; t++) {
#pragma unroll
        for (int r = 0; r < 4; r++) {
            int row = qt * BM + wave * 16 + quad * 4 + r;
            int col = l16 + 16 * t;
            size_t idx = ((size_t)bh * NSEQ + row) * DIM + col;
            float rv = res_isf ? ((const float*)res)[idx] : bf2f(((const u16*)res)[idx]);
            float v = R[t][r] + rv;
            v = (v < 0.f) ? 0.f : v;       // NaN-transparent relu
            if (out_isf) ((float*)outp)[idx] = v;
            else         ((u16*)outp)[idx]  = f2bf(v);
        }
    }
}

extern "C" void kernel_launch(void* const* d_in, const int* in_sizes, int n_in,
                              void* d_out, int out_size, void* d_ws, size_t ws_size,
                              hipStream_t stream) {
    const float* x  = (const float*)d_in[0];
    const float* W1 = (const float*)d_in[1];
    const float* W2 = (const float*)d_in[2];
    const float* a1 = (const float*)d_in[3];
    const float* a2 = (const float*)d_in[4];
    float* outp = (float*)d_out;

    size_t elems = (size_t)BH * NSEQ * DIM;        // 4,194,304
    u16* xn = (u16*)d_ws;                          // 8.39 MB
    u16* xT = xn + elems;                          // 8.39 MB
    u16* y1 = xT + elems;                          // 8.39 MB (layer-1 out, bf16)

    dim3 pgrid(BH * 16),     pblk(256);
    dim3 agrid(BH * QTILES), ablk(256);

    // layer 1: x (fp32) -> y1 (bf16)
    ContentGCN_5059471475267_prep<<<pgrid, pblk, 0, stream>>>(x, 1, xn, xT);
    ContentGCN_5059471475267_attn<<<agrid, ablk, 0, stream>>>(xn, xT, x, 1, W1, a1, y1, 0);
    // layer 2: y1 (bf16) -> d_out (fp32)
    ContentGCN_5059471475267_prep<<<pgrid, pblk, 0, stream>>>(y1, 0, xn, xT);
    ContentGCN_5059471475267_attn<<<agrid, ablk, 0, stream>>>(xn, xT, y1, 0, W2, a2, outp, 1);
}

// Round 12
// 345.655 us; speedup vs baseline: 2.0437x; 1.0756x over previous
//
#include <hip/hip_runtime.h>

typedef unsigned short u16;
typedef unsigned int   u32;
typedef __bf16 bf16x8 __attribute__((ext_vector_type(8)));  // MFMA A/B (4 VGPRs)
typedef float  f32x4  __attribute__((ext_vector_type(4)));  // MFMA C/D

#define BH    16
#define NSEQ  4096
#define DIM   64
#define BM    64            // Q rows per block (4 waves x 16)
#define BN    64            // K rows per tile
#define LDP   72            // K/V LDS row stride (u16): b128 ops uniform 8/bank (min)
#define LDPP  68            // P-strip row stride (u16): writes 2/bank, b64 reads 4/bank
#define NT    (NSEQ / BN)   // 64 K-tiles
#define QTILES (NSEQ / BM)  // 64

__device__ __forceinline__ float bf2f(u16 u) {
    union { u32 i; float f; } v; v.i = ((u32)u) << 16; return v.f;
}
__device__ __forceinline__ u16 f2bf(float f) {          // true RNE
    union { float f; u32 i; } v; v.f = f;
    u32 r = v.i + 0x7fffu + ((v.i >> 16) & 1u);
    return (u16)(r >> 16);
}
__device__ __forceinline__ u16 f2bf_fast(float f) {     // round-half-up, 2 VALU ops
    union { float f; u32 i; } v; v.f = f;
    return (u16)((v.i + 0x8000u) >> 16);
}
#if __has_builtin(__builtin_amdgcn_exp2f)
__device__ __forceinline__ float exp2_raw(float x) { return __builtin_amdgcn_exp2f(x); }
#else
__device__ __forceinline__ float exp2_raw(float x) {
    float r; asm("v_exp_f32 %0, %1" : "=v"(r) : "v"(x)); return r;
}
#endif

// LDS-only barrier: order ds ops across waves WITHOUT draining vmcnt.
// In-flight global prefetches (private regs) legally cross; the compiler
// auto-inserts vmcnt waits before their consuming ds_write.
__device__ __forceinline__ void lds_barrier() {
    asm volatile("s_waitcnt lgkmcnt(0)\n\ts_barrier" ::: "memory");
}

// ---------------------------------------------------------------------------
// prep: L2-normalize rows -> xn (bf16); transpose raw values -> xT (bf16)
// isf=1: src fp32; isf=0: src bf16. grid BH*16 x 256 (1 row/thread)
// ---------------------------------------------------------------------------
__global__ __launch_bounds__(256) void ContentGCN_5059471475267_prep(
    const void* __restrict__ src, int isf,
    u16* __restrict__ xn, u16* __restrict__ xT)
{
    __shared__ u16 tile[256 * 72];
    int bh = blockIdx.x >> 4, nt = blockIdx.x & 15, tid = threadIdx.x;
    size_t base = ((size_t)bh * NSEQ + nt * 256 + tid) * DIM;

    float v[64];
    if (isf) {
        const float4* g = (const float4*)((const float*)src + base);
#pragma unroll
        for (int i = 0; i < 16; i++) {
            float4 t4 = g[i];
            v[4*i] = t4.x; v[4*i+1] = t4.y; v[4*i+2] = t4.z; v[4*i+3] = t4.w;
        }
    } else {
        alignas(16) u16 tmp[64];
        const uint4* g = (const uint4*)((const u16*)src + base);
#pragma unroll
        for (int i = 0; i < 8; i++) ((uint4*)tmp)[i] = g[i];
#pragma unroll
        for (int d = 0; d < 64; d++) v[d] = bf2f(tmp[d]);
    }

    float ss = 0.f;
#pragma unroll
    for (int d = 0; d < 64; d++) ss += v[d] * v[d];
    float n = sqrtf(ss);
    if (n < 1e-12f) n = 1e-12f;            // F.normalize eps
    float inv = 1.0f / n;

    alignas(16) u16 nb[64], rb[64];
#pragma unroll
    for (int d = 0; d < 64; d++) { nb[d] = f2bf(v[d] * inv); rb[d] = f2bf(v[d]); }
    uint4* gn = (uint4*)(xn + base);
#pragma unroll
    for (int i = 0; i < 8; i++) gn[i] = ((uint4*)nb)[i];

    uint4* trow = (uint4*)&tile[tid * 72];
#pragma unroll
    for (int i = 0; i < 8; i++) trow[i] = ((uint4*)rb)[i];
    __syncthreads();

    int d = tid & 63, ch = tid >> 6;
    alignas(16) u16 ob[64];
#pragma unroll
    for (int nn = 0; nn < 64; nn++) ob[nn] = tile[(ch * 64 + nn) * 72 + d];
    uint4* gt = (uint4*)(xT + ((size_t)bh * DIM + d) * NSEQ + (size_t)nt * 256 + ch * 64);
#pragma unroll
    for (int i = 0; i < 8; i++) gt[i] = ((uint4*)ob)[i];
}

// ---------------------------------------------------------------------------
// attn: MFMA flash attention. Single-buffered K/V, two LDS-ONLY barriers per
// iter (no vmcnt drain -> prefetches stay in flight). Fixed-max softmax
// (diag cosine == 1). Row-sum l accumulated on the MATRIX pipe via an
// all-ones B operand (C-layout lands invl exactly where the epilogue needs
// it -> no shuffle reduction). 27.1 KB LDS.
// ---------------------------------------------------------------------------
__global__ __launch_bounds__(256) void ContentGCN_5059471475267_attn(
    const u16* __restrict__ xn, const u16* __restrict__ xT,
    const void* __restrict__ res, int res_isf,
    const float* __restrict__ Wt, const float* __restrict__ alphap,
    void* __restrict__ outp, int out_isf)
{
    __shared__ u16 sK[BN * LDP];        // K tile; W at epilogue
    __shared__ u16 sV[DIM * LDP];       // V^T: [d][k]
    __shared__ u16 sP[4 * 16 * LDPP];   // wave-private P strips

    int tid  = threadIdx.x;
    int wave = tid >> 6, lane = tid & 63;
    int quad = lane >> 4, l16 = lane & 15;
    int bh   = blockIdx.x >> 6;
    int qt   = blockIdx.x & 63;

    float scale = 1.4426950408889634f / fmaxf(alphap[0], 0.01f);  // exp2 domain

    // all-ones bf16 B operand (0x3F80 per element)
    union { u16 s[8]; bf16x8 v; } onesu;
#pragma unroll
    for (int i = 0; i < 8; i++) onesu.s[i] = 0x3F80;
    bf16x8 onesB = onesu.v;

    // Q fragments (A-layout: m=l16, k=quad*8+j)
    int qrow = qt * BM + wave * 16 + l16;
    size_t qbase = ((size_t)bh * NSEQ + qrow) * DIM;
    bf16x8 aQ0 = *(const bf16x8*)(xn + qbase + quad * 8);
    bf16x8 aQ1 = *(const bf16x8*)(xn + qbase + 32 + quad * 8);

    const f32x4 fzero = {0.f, 0.f, 0.f, 0.f};
    f32x4 O[4];
#pragma unroll
    for (int t = 0; t < 4; t++) O[t] = fzero;
    f32x4 l_acc = fzero;                // row sums of P, C-layout (row=quad*4+r)

    u16* sPw = sP + wave * (16 * LDPP);
    int srow = tid >> 2, scol = (tid & 3) * 16;   // staging: 16 u16/thread

    // staging pointers, constant bumps
    const u16* pk = xn + ((size_t)bh * NSEQ + srow) * DIM + scol;   // += BN*DIM
    const u16* pv = xT + ((size_t)bh * DIM + srow) * NSEQ + scol;   // += BN
    uint4 ck0 = ((const uint4*)pk)[0], ck1 = ((const uint4*)pk)[1];
    uint4 cv0 = ((const uint4*)pv)[0], cv1 = ((const uint4*)pv)[1];
    pk += (size_t)BN * DIM; pv += BN;

    for (int kt = 0; kt < NT; kt++) {
        lds_barrier();     // prior tile's LDS reads complete before overwrite
        *(uint4*)&sK[srow * LDP + scol]     = ck0;
        *(uint4*)&sK[srow * LDP + scol + 8] = ck1;
        *(uint4*)&sV[srow * LDP + scol]     = cv0;
        *(uint4*)&sV[srow * LDP + scol + 8] = cv1;
        if (kt + 1 < NT) {   // prefetch next tile; stays in flight across barrier
            ck0 = ((const uint4*)pk)[0]; ck1 = ((const uint4*)pk)[1];
            cv0 = ((const uint4*)pv)[0]; cv1 = ((const uint4*)pv)[1];
            pk += (size_t)BN * DIM; pv += BN;
        }
        lds_barrier();     // publish K/V tile (no vmcnt drain)

        // S = Qn @ Kn^T (16 rows x 64 cols per wave)
        f32x4 S[4];
#pragma unroll
        for (int t = 0; t < 4; t++) {
            bf16x8 b0 = *(const bf16x8*)&sK[(l16 + 16 * t) * LDP + quad * 8];
            bf16x8 b1 = *(const bf16x8*)&sK[(l16 + 16 * t) * LDP + 32 + quad * 8];
            f32x4 acc = fzero;
            acc = __builtin_amdgcn_mfma_f32_16x16x32_bf16(aQ0, b0, acc, 0, 0, 0);
            acc = __builtin_amdgcn_mfma_f32_16x16x32_bf16(aQ1, b1, acc, 0, 0, 0);
            S[t] = acc;
        }

        // fixed-max softmax: p = exp2(s*scale - scale); store bf16 P strip
#pragma unroll
        for (int r = 0; r < 4; r++) {
#pragma unroll
            for (int t = 0; t < 4; t++) {
                float p = exp2_raw(fmaf(S[t][r], scale, -scale));
                sPw[(quad * 4 + r) * LDPP + l16 + 16 * t] = f2bf_fast(p);
            }
        }

        // PV + row-sum: A = P (LDS round-trip), B = V^T rows / all-ones
        union { uint2 u[2]; bf16x8 v; } pA0, pA1;
        pA0.u[0] = *(const uint2*)&sPw[l16 * LDPP + quad * 8];
        pA0.u[1] = *(const uint2*)&sPw[l16 * LDPP + quad * 8 + 4];
        pA1.u[0] = *(const uint2*)&sPw[l16 * LDPP + 32 + quad * 8];
        pA1.u[1] = *(const uint2*)&sPw[l16 * LDPP + 32 + quad * 8 + 4];
        l_acc = __builtin_amdgcn_mfma_f32_16x16x32_bf16(pA0.v, onesB, l_acc, 0, 0, 0);
        l_acc = __builtin_amdgcn_mfma_f32_16x16x32_bf16(pA1.v, onesB, l_acc, 0, 0, 0);
#pragma unroll
        for (int t = 0; t < 4; t++) {
            bf16x8 b0 = *(const bf16x8*)&sV[(l16 + 16 * t) * LDP + quad * 8];
            bf16x8 b1 = *(const bf16x8*)&sV[(l16 + 16 * t) * LDP + 32 + quad * 8];
            O[t] = __builtin_amdgcn_mfma_f32_16x16x32_bf16(pA0.v, b0, O[t], 0, 0, 0);
            O[t] = __builtin_amdgcn_mfma_f32_16x16x32_bf16(pA1.v, b1, O[t], 0, 0, 0);
        }
    }

    // av = O / l -> sPw (bf16); l_acc is already per-lane-correct (C-layout)
#pragma unroll
    for (int r = 0; r < 4; r++) {
        float invl = 1.0f / l_acc[r];
#pragma unroll
        for (int t = 0; t < 4; t++)
            sPw[(quad * 4 + r) * LDPP + l16 + 16 * t] = f2bf_fast(O[t][r] * invl);
    }
    union { uint2 u[2]; bf16x8 v; } aA0, aA1;
    aA0.u[0] = *(const uint2*)&sPw[l16 * LDPP + quad * 8];
    aA0.u[1] = *(const uint2*)&sPw[l16 * LDPP + quad * 8 + 4];
    aA1.u[0] = *(const uint2*)&sPw[l16 * LDPP + 32 + quad * 8];
    aA1.u[1] = *(const uint2*)&sPw[l16 * LDPP + 32 + quad * 8 + 4];

    // stage W (fp32 -> bf16) into sK (dead after loop); full syncs (once)
    __syncthreads();
    {
        int r = tid >> 2, c0 = (tid & 3) * 16;
        alignas(16) u16 wb[16];
        const float4* gw = (const float4*)(Wt + r * DIM + c0);
#pragma unroll
        for (int i = 0; i < 4; i++) {
            float4 t4 = gw[i];
            wb[4*i]   = f2bf(t4.x); wb[4*i+1] = f2bf(t4.y);
            wb[4*i+2] = f2bf(t4.z); wb[4*i+3] = f2bf(t4.w);
        }
        *(uint4*)&sK[r * LDP + c0]     = ((uint4*)wb)[0];
        *(uint4*)&sK[r * LDP + c0 + 8] = ((uint4*)wb)[1];
    }
    __syncthreads();

    f32x4 R[4];
#pragma unroll
    for (int t = 0; t < 4; t++) {
        bf16x8 b0 = *(const bf16x8*)&sK[(l16 + 16 * t) * LDP + quad * 8];
        bf16x8 b1 = *(const bf16x8*)&sK[(l16 + 16 * t) * LDP + 32 + quad * 8];
        f32x4 acc = fzero;
        acc = __builtin_amdgcn_mfma_f32_16x16x32_bf16(aA0.v, b0, acc, 0, 0, 0);
        acc = __builtin_amdgcn_mfma_f32_16x16x32_bf16(aA1.v, b1, acc, 0, 0, 0);
        R[t] = acc;
    }
#pragma unroll
    for (int t = 0; t < 4; t++) {
#pragma unroll
        for (int r = 0; r < 4; r++) {
            int row = qt * BM + wave * 16 + quad * 4 + r;
            int col = l16 + 16 * t;
            size_t idx = ((size_t)bh * NSEQ + row) * DIM + col;
            float rv = res_isf ? ((const float*)res)[idx] : bf2f(((const u16*)res)[idx]);
            float v = R[t][r] + rv;
            v = (v < 0.f) ? 0.f : v;       // NaN-transparent relu
            if (out_isf) ((float*)outp)[idx] = v;
            else         ((u16*)outp)[idx]  = f2bf(v);
        }
    }
}

extern "C" void kernel_launch(void* const* d_in, const int* in_sizes, int n_in,
                              void* d_out, int out_size, void* d_ws, size_t ws_size,
                              hipStream_t stream) {
    const float* x  = (const float*)d_in[0];
    const float* W1 = (const float*)d_in[1];
    const float* W2 = (const float*)d_in[2];
    const float* a1 = (const float*)d_in[3];
    const float* a2 = (const float*)d_in[4];
    float* outp = (float*)d_out;

    size_t elems = (size_t)BH * NSEQ * DIM;        // 4,194,304
    u16* xn = (u16*)d_ws;                          // 8.39 MB
    u16* xT = xn + elems;                          // 8.39 MB
    u16* y1 = xT + elems;                          // 8.39 MB (layer-1 out, bf16)

    dim3 pgrid(BH * 16),     pblk(256);
    dim3 agrid(BH * QTILES), ablk(256);

    // layer 1: x (fp32) -> y1 (bf16)
    ContentGCN_5059471475267_prep<<<pgrid, pblk, 0, stream>>>(x, 1, xn, xT);
    ContentGCN_5059471475267_attn<<<agrid, ablk, 0, stream>>>(xn, xT, x, 1, W1, a1, y1, 0);
    // layer 2: y1 (bf16) -> d_out (fp32)
    ContentGCN_5059471475267_prep<<<pgrid, pblk, 0, stream>>>(y1, 0, xn, xT);
    ContentGCN_5059471475267_attn<<<agrid, ablk, 0, stream>>>(xn, xT, y1, 0, W2, a2, outp, 1);
}

// Round 13
// 338.172 us; speedup vs baseline: 2.0889x; 1.0221x over previous
//
#include <hip/hip_runtime.h>

typedef unsigned short u16;
typedef unsigned int   u32;
typedef __bf16 bf16x8 __attribute__((ext_vector_type(8)));  // MFMA A/B (4 VGPRs)
typedef float  f32x4  __attribute__((ext_vector_type(4)));  // MFMA C/D

#define BH    16
#define NSEQ  4096
#define DIM   64
#define BM    128           // Q rows per block (4 waves x 2 strips x 16)
#define BN    64            // K rows per tile
#define LDP   72            // K/V LDS row stride (u16): b128 ops uniform 8/bank (min)
#define LDPP  68            // P-strip row stride (u16): writes 2/bank, b64 reads 4/bank
#define NT    (NSEQ / BN)   // 64 K-tiles
#define QTILES (NSEQ / BM)  // 32

__device__ __forceinline__ float bf2f(u16 u) {
    union { u32 i; float f; } v; v.i = ((u32)u) << 16; return v.f;
}
__device__ __forceinline__ u16 f2bf(float f) {          // true RNE
    union { float f; u32 i; } v; v.f = f;
    u32 r = v.i + 0x7fffu + ((v.i >> 16) & 1u);
    return (u16)(r >> 16);
}
__device__ __forceinline__ u16 f2bf_fast(float f) {     // round-half-up, 2 VALU ops
    union { float f; u32 i; } v; v.f = f;
    return (u16)((v.i + 0x8000u) >> 16);
}
#if __has_builtin(__builtin_amdgcn_exp2f)
__device__ __forceinline__ float exp2_raw(float x) { return __builtin_amdgcn_exp2f(x); }
#else
__device__ __forceinline__ float exp2_raw(float x) {
    float r; asm("v_exp_f32 %0, %1" : "=v"(r) : "v"(x)); return r;
}
#endif

// LDS-only barrier: order ds ops across waves WITHOUT draining vmcnt.
__device__ __forceinline__ void lds_barrier() {
    asm volatile("s_waitcnt lgkmcnt(0)\n\ts_barrier" ::: "memory");
}

// ---------------------------------------------------------------------------
// prep: L2-normalize rows -> xn (bf16); transpose raw values -> xT (bf16)
// isf=1: src fp32; isf=0: src bf16. grid BH*16 x 256 (1 row/thread)
// ---------------------------------------------------------------------------
__global__ __launch_bounds__(256) void ContentGCN_5059471475267_prep(
    const void* __restrict__ src, int isf,
    u16* __restrict__ xn, u16* __restrict__ xT)
{
    __shared__ u16 tile[256 * 72];
    int bh = blockIdx.x >> 4, nt = blockIdx.x & 15, tid = threadIdx.x;
    size_t base = ((size_t)bh * NSEQ + nt * 256 + tid) * DIM;

    float v[64];
    if (isf) {
        const float4* g = (const float4*)((const float*)src + base);
#pragma unroll
        for (int i = 0; i < 16; i++) {
            float4 t4 = g[i];
            v[4*i] = t4.x; v[4*i+1] = t4.y; v[4*i+2] = t4.z; v[4*i+3] = t4.w;
        }
    } else {
        alignas(16) u16 tmp[64];
        const uint4* g = (const uint4*)((const u16*)src + base);
#pragma unroll
        for (int i = 0; i < 8; i++) ((uint4*)tmp)[i] = g[i];
#pragma unroll
        for (int d = 0; d < 64; d++) v[d] = bf2f(tmp[d]);
    }

    float ss = 0.f;
#pragma unroll
    for (int d = 0; d < 64; d++) ss += v[d] * v[d];
    float n = sqrtf(ss);
    if (n < 1e-12f) n = 1e-12f;            // F.normalize eps
    float inv = 1.0f / n;

    alignas(16) u16 nb[64], rb[64];
#pragma unroll
    for (int d = 0; d < 64; d++) { nb[d] = f2bf(v[d] * inv); rb[d] = f2bf(v[d]); }
    uint4* gn = (uint4*)(xn + base);
#pragma unroll
    for (int i = 0; i < 8; i++) gn[i] = ((uint4*)nb)[i];

    uint4* trow = (uint4*)&tile[tid * 72];
#pragma unroll
    for (int i = 0; i < 8; i++) trow[i] = ((uint4*)rb)[i];
    __syncthreads();

    int d = tid & 63, ch = tid >> 6;
    alignas(16) u16 ob[64];
#pragma unroll
    for (int nn = 0; nn < 64; nn++) ob[nn] = tile[(ch * 64 + nn) * 72 + d];
    uint4* gt = (uint4*)(xT + ((size_t)bh * DIM + d) * NSEQ + (size_t)nt * 256 + ch * 64);
#pragma unroll
    for (int i = 0; i < 8; i++) gt[i] = ((uint4*)ob)[i];
}

// ---------------------------------------------------------------------------
// attn: MFMA flash attention, BM=128: each wave owns TWO 16-row Q strips, so
// K/V LDS fragments are read once per iter and reused from registers for both
// strips (1.86x less LDS traffic per unit work — LDS pipe is the bottleneck).
// Single-buffered K/V, lds-only barriers, fixed-max softmax, MFMA row-sums.
// P strip buffer reused strip0-then-strip1 (wave-private, same-wave DS order).
// ---------------------------------------------------------------------------
__global__ __launch_bounds__(256) void ContentGCN_5059471475267_attn(
    const u16* __restrict__ xn, const u16* __restrict__ xT,
    const void* __restrict__ res, int res_isf,
    const float* __restrict__ Wt, const float* __restrict__ alphap,
    void* __restrict__ outp, int out_isf)
{
    __shared__ u16 sK[BN * LDP];        // K tile; W at epilogue
    __shared__ u16 sV[DIM * LDP];       // V^T: [d][k]
    __shared__ u16 sP[4 * 16 * LDPP];   // wave-private P strip (reused per strip)

    int tid  = threadIdx.x;
    int wave = tid >> 6, lane = tid & 63;
    int quad = lane >> 4, l16 = lane & 15;
    int bh   = blockIdx.x >> 5;         // QTILES = 32
    int qt   = blockIdx.x & 31;

    float scale = 1.4426950408889634f / fmaxf(alphap[0], 0.01f);  // exp2 domain

    union { u16 s[8]; bf16x8 v; } onesu;
#pragma unroll
    for (int i = 0; i < 8; i++) onesu.s[i] = 0x3F80;
    bf16x8 onesB = onesu.v;

    // Q fragments, two strips (A-layout: m=l16, k=quad*8+j)
    int qrowA = qt * BM + wave * 16 + l16;            // strip0: rows wave*16+
    size_t qbaseA = ((size_t)bh * NSEQ + qrowA) * DIM;
    size_t qbaseB = qbaseA + (size_t)64 * DIM;        // strip1: +64 rows
    bf16x8 aQ00 = *(const bf16x8*)(xn + qbaseA + quad * 8);
    bf16x8 aQ01 = *(const bf16x8*)(xn + qbaseA + 32 + quad * 8);
    bf16x8 aQ10 = *(const bf16x8*)(xn + qbaseB + quad * 8);
    bf16x8 aQ11 = *(const bf16x8*)(xn + qbaseB + 32 + quad * 8);

    const f32x4 fzero = {0.f, 0.f, 0.f, 0.f};
    f32x4 O0[4], O1[4];
#pragma unroll
    for (int t = 0; t < 4; t++) { O0[t] = fzero; O1[t] = fzero; }
    f32x4 l0 = fzero, l1 = fzero;       // row sums of P, C-layout

    u16* sPw = sP + wave * (16 * LDPP);
    int srow = tid >> 2, scol = (tid & 3) * 16;   // staging: 16 u16/thread

    const u16* pk = xn + ((size_t)bh * NSEQ + srow) * DIM + scol;   // += BN*DIM
    const u16* pv = xT + ((size_t)bh * DIM + srow) * NSEQ + scol;   // += BN
    uint4 ck0 = ((const uint4*)pk)[0], ck1 = ((const uint4*)pk)[1];
    uint4 cv0 = ((const uint4*)pv)[0], cv1 = ((const uint4*)pv)[1];
    pk += (size_t)BN * DIM; pv += BN;

    for (int kt = 0; kt < NT; kt++) {
        lds_barrier();     // prior tile's LDS reads complete before overwrite
        *(uint4*)&sK[srow * LDP + scol]     = ck0;
        *(uint4*)&sK[srow * LDP + scol + 8] = ck1;
        *(uint4*)&sV[srow * LDP + scol]     = cv0;
        *(uint4*)&sV[srow * LDP + scol + 8] = cv1;
        if (kt + 1 < NT) {   // prefetch next tile; stays in flight across barrier
            ck0 = ((const uint4*)pk)[0]; ck1 = ((const uint4*)pk)[1];
            cv0 = ((const uint4*)pv)[0]; cv1 = ((const uint4*)pv)[1];
            pk += (size_t)BN * DIM; pv += BN;
        }
        lds_barrier();     // publish K/V tile (no vmcnt drain)

        // S for BOTH strips: each K fragment read once, used twice
        f32x4 S0[4], S1[4];
#pragma unroll
        for (int t = 0; t < 4; t++) {
            bf16x8 b0 = *(const bf16x8*)&sK[(l16 + 16 * t) * LDP + quad * 8];
            bf16x8 b1 = *(const bf16x8*)&sK[(l16 + 16 * t) * LDP + 32 + quad * 8];
            S0[t] = __builtin_amdgcn_mfma_f32_16x16x32_bf16(aQ01, b1,
                    __builtin_amdgcn_mfma_f32_16x16x32_bf16(aQ00, b0, fzero, 0, 0, 0), 0, 0, 0);
            S1[t] = __builtin_amdgcn_mfma_f32_16x16x32_bf16(aQ11, b1,
                    __builtin_amdgcn_mfma_f32_16x16x32_bf16(aQ10, b0, fzero, 0, 0, 0), 0, 0, 0);
        }

        // strip0: fixed-max softmax -> P round-trip -> A frags + l mfma
        union { uint2 u[2]; bf16x8 v; } pA00, pA01, pA10, pA11;
#pragma unroll
        for (int r = 0; r < 4; r++)
#pragma unroll
            for (int t = 0; t < 4; t++)
                sPw[(quad * 4 + r) * LDPP + l16 + 16 * t] =
                    f2bf_fast(exp2_raw(fmaf(S0[t][r], scale, -scale)));
        pA00.u[0] = *(const uint2*)&sPw[l16 * LDPP + quad * 8];
        pA00.u[1] = *(const uint2*)&sPw[l16 * LDPP + quad * 8 + 4];
        pA01.u[0] = *(const uint2*)&sPw[l16 * LDPP + 32 + quad * 8];
        pA01.u[1] = *(const uint2*)&sPw[l16 * LDPP + 32 + quad * 8 + 4];
        l0 = __builtin_amdgcn_mfma_f32_16x16x32_bf16(pA00.v, onesB, l0, 0, 0, 0);
        l0 = __builtin_amdgcn_mfma_f32_16x16x32_bf16(pA01.v, onesB, l0, 0, 0, 0);

        // strip1 (same sPw region; same-wave DS ordering makes this safe)
#pragma unroll
        for (int r = 0; r < 4; r++)
#pragma unroll
            for (int t = 0; t < 4; t++)
                sPw[(quad * 4 + r) * LDPP + l16 + 16 * t] =
                    f2bf_fast(exp2_raw(fmaf(S1[t][r], scale, -scale)));
        pA10.u[0] = *(const uint2*)&sPw[l16 * LDPP + quad * 8];
        pA10.u[1] = *(const uint2*)&sPw[l16 * LDPP + quad * 8 + 4];
        pA11.u[0] = *(const uint2*)&sPw[l16 * LDPP + 32 + quad * 8];
        pA11.u[1] = *(const uint2*)&sPw[l16 * LDPP + 32 + quad * 8 + 4];
        l1 = __builtin_amdgcn_mfma_f32_16x16x32_bf16(pA10.v, onesB, l1, 0, 0, 0);
        l1 = __builtin_amdgcn_mfma_f32_16x16x32_bf16(pA11.v, onesB, l1, 0, 0, 0);

        // PV for BOTH strips: each V fragment read once, used twice
#pragma unroll
        for (int t = 0; t < 4; t++) {
            bf16x8 vb0 = *(const bf16x8*)&sV[(l16 + 16 * t) * LDP + quad * 8];
            bf16x8 vb1 = *(const bf16x8*)&sV[(l16 + 16 * t) * LDP + 32 + quad * 8];
            O0[t] = __builtin_amdgcn_mfma_f32_16x16x32_bf16(pA01.v, vb1,
                    __builtin_amdgcn_mfma_f32_16x16x32_bf16(pA00.v, vb0, O0[t], 0, 0, 0), 0, 0, 0);
            O1[t] = __builtin_amdgcn_mfma_f32_16x16x32_bf16(pA11.v, vb1,
                    __builtin_amdgcn_mfma_f32_16x16x32_bf16(pA10.v, vb0, O1[t], 0, 0, 0), 0, 0, 0);
        }
    }

    // av = O / l -> sPw -> A frags, per strip (sequential reuse, wave-private)
    union { uint2 u[2]; bf16x8 v; } aA00, aA01, aA10, aA11;
#pragma unroll
    for (int r = 0; r < 4; r++) {
        float invl = 1.0f / l0[r];
#pragma unroll
        for (int t = 0; t < 4; t++)
            sPw[(quad * 4 + r) * LDPP + l16 + 16 * t] = f2bf_fast(O0[t][r] * invl);
    }
    aA00.u[0] = *(const uint2*)&sPw[l16 * LDPP + quad * 8];
    aA00.u[1] = *(const uint2*)&sPw[l16 * LDPP + quad * 8 + 4];
    aA01.u[0] = *(const uint2*)&sPw[l16 * LDPP + 32 + quad * 8];
    aA01.u[1] = *(const uint2*)&sPw[l16 * LDPP + 32 + quad * 8 + 4];
#pragma unroll
    for (int r = 0; r < 4; r++) {
        float invl = 1.0f / l1[r];
#pragma unroll
        for (int t = 0; t < 4; t++)
            sPw[(quad * 4 + r) * LDPP + l16 + 16 * t] = f2bf_fast(O1[t][r] * invl);
    }
    aA10.u[0] = *(const uint2*)&sPw[l16 * LDPP + quad * 8];
    aA10.u[1] = *(const uint2*)&sPw[l16 * LDPP + quad * 8 + 4];
    aA11.u[0] = *(const uint2*)&sPw[l16 * LDPP + 32 + quad * 8];
    aA11.u[1] = *(const uint2*)&sPw[l16 * LDPP + 32 + quad * 8 + 4];

    // stage W (fp32 -> bf16) into sK (dead after loop)
    __syncthreads();
    {
        int r = tid >> 2, c0 = (tid & 3) * 16;
        alignas(16) u16 wb[16];
        const float4* gw = (const float4*)(Wt + r * DIM + c0);
#pragma unroll
        for (int i = 0; i < 4; i++) {
            float4 t4 = gw[i];
            wb[4*i]   = f2bf(t4.x); wb[4*i+1] = f2bf(t4.y);
            wb[4*i+2] = f2bf(t4.z); wb[4*i+3] = f2bf(t4.w);
        }
        *(uint4*)&sK[r * LDP + c0]     = ((uint4*)wb)[0];
        *(uint4*)&sK[r * LDP + c0 + 8] = ((uint4*)wb)[1];
    }
    __syncthreads();

    // out = relu(av @ W^T + res), both strips (W frags read once, used twice)
    f32x4 R0[4], R1[4];
#pragma unroll
    for (int t = 0; t < 4; t++) {
        bf16x8 b0 = *(const bf16x8*)&sK[(l16 + 16 * t) * LDP + quad * 8];
        bf16x8 b1 = *(const bf16x8*)&sK[(l16 + 16 * t) * LDP + 32 + quad * 8];
        R0[t] = __builtin_amdgcn_mfma_f32_16x16x32_bf16(aA01.v, b1,
                __builtin_amdgcn_mfma_f32_16x16x32_bf16(aA00.v, b0, fzero, 0, 0, 0), 0, 0, 0);
        R1[t] = __builtin_amdgcn_mfma_f32_16x16x32_bf16(aA11.v, b1,
                __builtin_amdgcn_mfma_f32_16x16x32_bf16(aA10.v, b0, fzero, 0, 0, 0), 0, 0, 0);
    }
#pragma unroll
    for (int s = 0; s < 2; s++) {
#pragma unroll
        for (int t = 0; t < 4; t++) {
#pragma unroll
            for (int r = 0; r < 4; r++) {
                int row = qt * BM + wave * 16 + s * 64 + quad * 4 + r;
                int col = l16 + 16 * t;
                size_t idx = ((size_t)bh * NSEQ + row) * DIM + col;
                float rr = (s == 0) ? R0[t][r] : R1[t][r];
                float rv = res_isf ? ((const float*)res)[idx] : bf2f(((const u16*)res)[idx]);
                float v = rr + rv;
                v = (v < 0.f) ? 0.f : v;   // NaN-transparent relu
                if (out_isf) ((float*)outp)[idx] = v;
                else         ((u16*)outp)[idx]  = f2bf(v);
            }
        }
    }
}

extern "C" void kernel_launch(void* const* d_in, const int* in_sizes, int n_in,
                              void* d_out, int out_size, void* d_ws, size_t ws_size,
                              hipStream_t stream) {
    const float* x  = (const float*)d_in[0];
    const float* W1 = (const float*)d_in[1];
    const float* W2 = (const float*)d_in[2];
    const float* a1 = (const float*)d_in[3];
    const float* a2 = (const float*)d_in[4];
    float* outp = (float*)d_out;

    size_t elems = (size_t)BH * NSEQ * DIM;        // 4,194,304
    u16* xn = (u16*)d_ws;                          // 8.39 MB
    u16* xT = xn + elems;                          // 8.39 MB
    u16* y1 = xT + elems;                          // 8.39 MB (layer-1 out, bf16)

    dim3 pgrid(BH * 16),     pblk(256);
    dim3 agrid(BH * QTILES), ablk(256);            // 512 blocks = 2/CU

    // layer 1: x (fp32) -> y1 (bf16)
    ContentGCN_5059471475267_prep<<<pgrid, pblk, 0, stream>>>(x, 1, xn, xT);
    ContentGCN_5059471475267_attn<<<agrid, ablk, 0, stream>>>(xn, xT, x, 1, W1, a1, y1, 0);
    // layer 2: y1 (bf16) -> d_out (fp32)
    ContentGCN_5059471475267_prep<<<pgrid, pblk, 0, stream>>>(y1, 0, xn, xT);
    ContentGCN_5059471475267_attn<<<agrid, ablk, 0, stream>>>(xn, xT, y1, 0, W2, a2, outp, 1);
}

// Round 14
// 279.996 us; speedup vs baseline: 2.5229x; 1.2078x over previous
//
#include <hip/hip_runtime.h>

typedef unsigned short u16;
typedef unsigned int   u32;
typedef __bf16 bf16x8 __attribute__((ext_vector_type(8)));  // MFMA A/B (4 VGPRs)
typedef float  f32x4  __attribute__((ext_vector_type(4)));  // MFMA C/D

#define BH    16
#define NSEQ  4096
#define DIM   64
#define BM    128           // Q rows per block (4 strips-waves x 2 x 16)
#define BN    64            // K rows per tile
#define LDP   72            // K/V LDS row stride (u16): b128 ops uniform 8/bank
#define LDPP  68            // P-strip row stride (u16)
#define NTH   32            // K-tiles per half (2 halves x 32 = 64)
#define QTILES (NSEQ / BM)  // 32

// smem carve (u16 units): sK [2][64*72] | sV [2][64*72] | sP [8][16*68]
#define SMEM_U16   27136    // 54272 B
#define SK_OFF     0
#define SV_OFF     9216
#define SP_OFF     18432
#define HBUF       4608     // one half's K or V buffer (64*72)
// epilogue overlays (u16 offsets): O-scratch [0..8192), l-scratch [8192..12288),
// W [13824..18432) — all disjoint; sP region untouched.
#define WOFF       13824

__device__ __forceinline__ float bf2f(u16 u) {
    union { u32 i; float f; } v; v.i = ((u32)u) << 16; return v.f;
}
__device__ __forceinline__ u16 f2bf(float f) {          // true RNE
    union { float f; u32 i; } v; v.f = f;
    u32 r = v.i + 0x7fffu + ((v.i >> 16) & 1u);
    return (u16)(r >> 16);
}
__device__ __forceinline__ u16 f2bf_fast(float f) {     // round-half-up
    union { float f; u32 i; } v; v.f = f;
    return (u16)((v.i + 0x8000u) >> 16);
}
#if __has_builtin(__builtin_amdgcn_exp2f)
__device__ __forceinline__ float exp2_raw(float x) { return __builtin_amdgcn_exp2f(x); }
#else
__device__ __forceinline__ float exp2_raw(float x) {
    float r; asm("v_exp_f32 %0, %1" : "=v"(r) : "v"(x)); return r;
}
#endif

// LDS-only barrier: order ds ops across waves WITHOUT draining vmcnt.
__device__ __forceinline__ void lds_barrier() {
    asm volatile("s_waitcnt lgkmcnt(0)\n\ts_barrier" ::: "memory");
}

// ---------------------------------------------------------------------------
// prep: L2-normalize rows -> xn (bf16); transpose raw values -> xT (bf16)
// ---------------------------------------------------------------------------
__global__ __launch_bounds__(256) void ContentGCN_5059471475267_prep(
    const void* __restrict__ src, int isf,
    u16* __restrict__ xn, u16* __restrict__ xT)
{
    __shared__ u16 tile[256 * 72];
    int bh = blockIdx.x >> 4, nt = blockIdx.x & 15, tid = threadIdx.x;
    size_t base = ((size_t)bh * NSEQ + nt * 256 + tid) * DIM;

    float v[64];
    if (isf) {
        const float4* g = (const float4*)((const float*)src + base);
#pragma unroll
        for (int i = 0; i < 16; i++) {
            float4 t4 = g[i];
            v[4*i] = t4.x; v[4*i+1] = t4.y; v[4*i+2] = t4.z; v[4*i+3] = t4.w;
        }
    } else {
        alignas(16) u16 tmp[64];
        const uint4* g = (const uint4*)((const u16*)src + base);
#pragma unroll
        for (int i = 0; i < 8; i++) ((uint4*)tmp)[i] = g[i];
#pragma unroll
        for (int d = 0; d < 64; d++) v[d] = bf2f(tmp[d]);
    }

    float ss = 0.f;
#pragma unroll
    for (int d = 0; d < 64; d++) ss += v[d] * v[d];
    float n = sqrtf(ss);
    if (n < 1e-12f) n = 1e-12f;            // F.normalize eps
    float inv = 1.0f / n;

    alignas(16) u16 nb[64], rb[64];
#pragma unroll
    for (int d = 0; d < 64; d++) { nb[d] = f2bf(v[d] * inv); rb[d] = f2bf(v[d]); }
    uint4* gn = (uint4*)(xn + base);
#pragma unroll
    for (int i = 0; i < 8; i++) gn[i] = ((uint4*)nb)[i];

    uint4* trow = (uint4*)&tile[tid * 72];
#pragma unroll
    for (int i = 0; i < 8; i++) trow[i] = ((uint4*)rb)[i];
    __syncthreads();

    int d = tid & 63, ch = tid >> 6;
    alignas(16) u16 ob[64];
#pragma unroll
    for (int nn = 0; nn < 64; nn++) ob[nn] = tile[(ch * 64 + nn) * 72 + d];
    uint4* gt = (uint4*)(xT + ((size_t)bh * DIM + d) * NSEQ + (size_t)nt * 256 + ch * 64);
#pragma unroll
    for (int i = 0; i < 8; i++) gt[i] = ((uint4*)ob)[i];
}

// ---------------------------------------------------------------------------
// attn: MFMA flash attention, BM=128, 512 threads (8 waves). K-SPLIT across
// wave halves: waves 0-3 do K-tiles 0..31, waves 4-7 do 32..63 -> 16 waves/CU
// (2x latency hiding vs R13) at unchanged LDS traffic per unit work.
// Fixed-max softmax partials merge exactly (no rescale): O=Oa+Ob, l=la+lb via
// one LDS exchange. Each wave keeps strip s=half in the epilogue.
// ---------------------------------------------------------------------------
__global__ __launch_bounds__(512, 4) void ContentGCN_5059471475267_attn(
    const u16* __restrict__ xn, const u16* __restrict__ xT,
    const void* __restrict__ res, int res_isf,
    const float* __restrict__ Wt, const float* __restrict__ alphap,
    void* __restrict__ outp, int out_isf)
{
    __shared__ u16 smem[SMEM_U16];
    u16* sK = smem + SK_OFF;
    u16* sV = smem + SV_OFF;
    u16* sP = smem + SP_OFF;

    int tid  = threadIdx.x;
    int w    = tid >> 6, lane = tid & 63;
    int half = w >> 2,  wv   = w & 3;
    int quad = lane >> 4, l16 = lane & 15;
    int bh   = blockIdx.x >> 5;         // QTILES = 32
    int qt   = blockIdx.x & 31;

    float scale = 1.4426950408889634f / fmaxf(alphap[0], 0.01f);  // exp2 domain

    union { u16 s[8]; bf16x8 v; } onesu;
#pragma unroll
    for (int i = 0; i < 8; i++) onesu.s[i] = 0x3F80;
    bf16x8 onesB = onesu.v;

    // Q fragments, two strips (rows wv*16 + s*64); both halves compute same rows
    int qrowA = qt * BM + wv * 16 + l16;
    size_t qbaseA = ((size_t)bh * NSEQ + qrowA) * DIM;
    size_t qbaseB = qbaseA + (size_t)64 * DIM;
    bf16x8 aQ00 = *(const bf16x8*)(xn + qbaseA + quad * 8);
    bf16x8 aQ01 = *(const bf16x8*)(xn + qbaseA + 32 + quad * 8);
    bf16x8 aQ10 = *(const bf16x8*)(xn + qbaseB + quad * 8);
    bf16x8 aQ11 = *(const bf16x8*)(xn + qbaseB + 32 + quad * 8);

    const f32x4 fzero = {0.f, 0.f, 0.f, 0.f};
    f32x4 O0[4], O1[4];
#pragma unroll
    for (int t = 0; t < 4; t++) { O0[t] = fzero; O1[t] = fzero; }
    f32x4 l0 = fzero, l1 = fzero;

    u16* sKh = sK + half * HBUF;
    u16* sVh = sV + half * HBUF;
    u16* sPw = sP + w * (16 * LDPP);

    int ltid = tid & 255;
    int srow = ltid >> 2, scol = (ltid & 3) * 16;   // per-half staging

    const u16* pk = xn + ((size_t)bh * NSEQ + half * (NTH * BN) + srow) * DIM + scol;
    const u16* pv = xT + ((size_t)bh * DIM + srow) * NSEQ + half * (NTH * BN) + scol;
    uint4 ck0 = ((const uint4*)pk)[0], ck1 = ((const uint4*)pk)[1];
    uint4 cv0 = ((const uint4*)pv)[0], cv1 = ((const uint4*)pv)[1];
    pk += (size_t)BN * DIM; pv += BN;

    for (int kt = 0; kt < NTH; kt++) {
        lds_barrier();     // prior tile's LDS reads complete before overwrite
        *(uint4*)&sKh[srow * LDP + scol]     = ck0;
        *(uint4*)&sKh[srow * LDP + scol + 8] = ck1;
        *(uint4*)&sVh[srow * LDP + scol]     = cv0;
        *(uint4*)&sVh[srow * LDP + scol + 8] = cv1;
        if (kt + 1 < NTH) {   // prefetch; stays in flight across barrier
            ck0 = ((const uint4*)pk)[0]; ck1 = ((const uint4*)pk)[1];
            cv0 = ((const uint4*)pv)[0]; cv1 = ((const uint4*)pv)[1];
            pk += (size_t)BN * DIM; pv += BN;
        }
        lds_barrier();     // publish K/V tile (no vmcnt drain)

        // S for both strips: K fragments read once, used twice
        f32x4 S0[4], S1[4];
#pragma unroll
        for (int t = 0; t < 4; t++) {
            bf16x8 b0 = *(const bf16x8*)&sKh[(l16 + 16 * t) * LDP + quad * 8];
            bf16x8 b1 = *(const bf16x8*)&sKh[(l16 + 16 * t) * LDP + 32 + quad * 8];
            S0[t] = __builtin_amdgcn_mfma_f32_16x16x32_bf16(aQ01, b1,
                    __builtin_amdgcn_mfma_f32_16x16x32_bf16(aQ00, b0, fzero, 0, 0, 0), 0, 0, 0);
            S1[t] = __builtin_amdgcn_mfma_f32_16x16x32_bf16(aQ11, b1,
                    __builtin_amdgcn_mfma_f32_16x16x32_bf16(aQ10, b0, fzero, 0, 0, 0), 0, 0, 0);
        }

        // fixed-max softmax + P round-trip, strip0 then strip1 (wave-private)
        union { uint2 u[2]; bf16x8 v; } pA00, pA01, pA10, pA11;
#pragma unroll
        for (int r = 0; r < 4; r++)
#pragma unroll
            for (int t = 0; t < 4; t++)
                sPw[(quad * 4 + r) * LDPP + l16 + 16 * t] =
                    f2bf_fast(exp2_raw(fmaf(S0[t][r], scale, -scale)));
        pA00.u[0] = *(const uint2*)&sPw[l16 * LDPP + quad * 8];
        pA00.u[1] = *(const uint2*)&sPw[l16 * LDPP + quad * 8 + 4];
        pA01.u[0] = *(const uint2*)&sPw[l16 * LDPP + 32 + quad * 8];
        pA01.u[1] = *(const uint2*)&sPw[l16 * LDPP + 32 + quad * 8 + 4];
        l0 = __builtin_amdgcn_mfma_f32_16x16x32_bf16(pA00.v, onesB, l0, 0, 0, 0);
        l0 = __builtin_amdgcn_mfma_f32_16x16x32_bf16(pA01.v, onesB, l0, 0, 0, 0);

#pragma unroll
        for (int r = 0; r < 4; r++)
#pragma unroll
            for (int t = 0; t < 4; t++)
                sPw[(quad * 4 + r) * LDPP + l16 + 16 * t] =
                    f2bf_fast(exp2_raw(fmaf(S1[t][r], scale, -scale)));
        pA10.u[0] = *(const uint2*)&sPw[l16 * LDPP + quad * 8];
        pA10.u[1] = *(const uint2*)&sPw[l16 * LDPP + quad * 8 + 4];
        pA11.u[0] = *(const uint2*)&sPw[l16 * LDPP + 32 + quad * 8];
        pA11.u[1] = *(const uint2*)&sPw[l16 * LDPP + 32 + quad * 8 + 4];
        l1 = __builtin_amdgcn_mfma_f32_16x16x32_bf16(pA10.v, onesB, l1, 0, 0, 0);
        l1 = __builtin_amdgcn_mfma_f32_16x16x32_bf16(pA11.v, onesB, l1, 0, 0, 0);

        // PV both strips: V fragments read once, used twice
#pragma unroll
        for (int t = 0; t < 4; t++) {
            bf16x8 vb0 = *(const bf16x8*)&sVh[(l16 + 16 * t) * LDP + quad * 8];
            bf16x8 vb1 = *(const bf16x8*)&sVh[(l16 + 16 * t) * LDP + 32 + quad * 8];
            O0[t] = __builtin_amdgcn_mfma_f32_16x16x32_bf16(pA01.v, vb1,
                    __builtin_amdgcn_mfma_f32_16x16x32_bf16(pA00.v, vb0, O0[t], 0, 0, 0), 0, 0, 0);
            O1[t] = __builtin_amdgcn_mfma_f32_16x16x32_bf16(pA11.v, vb1,
                    __builtin_amdgcn_mfma_f32_16x16x32_bf16(pA10.v, vb0, O1[t], 0, 0, 0), 0, 0, 0);
        }
    }

    __syncthreads();   // full drain: loop LDS reads done, smem reusable

    // exchange: each wave publishes its NON-owned strip (s = 1-half) partials.
    // O as bf16 (2 uint4/thread at smem[tid*16]), l as fp32x4 at byte 16384.
    {
        f32x4* Oo = (half == 0) ? O1 : O0;
        f32x4  lo = (half == 0) ? l1 : l0;
        alignas(16) u16 ob[16];
#pragma unroll
        for (int t = 0; t < 4; t++)
#pragma unroll
            for (int r = 0; r < 4; r++) ob[t * 4 + r] = f2bf(Oo[t][r]);
        *(uint4*)&smem[tid * 16]     = ((uint4*)ob)[0];
        *(uint4*)&smem[tid * 16 + 8] = ((uint4*)ob)[1];
        float4* lsc = (float4*)(smem + 8192);
        lsc[tid] = make_float4(lo[0], lo[1], lo[2], lo[3]);
    }
    // stage W (fp32 -> bf16) into its own region (no overlap with scratch)
    {
        int r = tid >> 3, c0 = (tid & 7) * 8;
        const float4* gw = (const float4*)(Wt + r * DIM + c0);
        float4 t0 = gw[0], t1 = gw[1];
        alignas(16) u16 wb[8];
        wb[0] = f2bf(t0.x); wb[1] = f2bf(t0.y); wb[2] = f2bf(t0.z); wb[3] = f2bf(t0.w);
        wb[4] = f2bf(t1.x); wb[5] = f2bf(t1.y); wb[6] = f2bf(t1.z); wb[7] = f2bf(t1.w);
        *(uint4*)&smem[WOFF + r * LDP + c0] = *(uint4*)wb;
    }
    __syncthreads();   // scratch + W visible

    // combine own strip (s = half) with partner's published partial
    f32x4* Om = (half == 0) ? O0 : O1;
    f32x4  lm = (half == 0) ? l0 : l1;
    {
        int partner = tid ^ 256;
        alignas(16) u16 ob[16];
        ((uint4*)ob)[0] = *(const uint4*)&smem[partner * 16];
        ((uint4*)ob)[1] = *(const uint4*)&smem[partner * 16 + 8];
#pragma unroll
        for (int t = 0; t < 4; t++)
#pragma unroll
            for (int r = 0; r < 4; r++) Om[t][r] += bf2f(ob[t * 4 + r]);
        float4 lp = ((const float4*)(smem + 8192))[partner];
        lm[0] += lp.x; lm[1] += lp.y; lm[2] += lp.z; lm[3] += lp.w;
    }

    // av = O/l -> sPw -> A frags (wave-private; sPw disjoint from overlays)
#pragma unroll
    for (int r = 0; r < 4; r++) {
        float invl = 1.0f / lm[r];
#pragma unroll
        for (int t = 0; t < 4; t++)
            sPw[(quad * 4 + r) * LDPP + l16 + 16 * t] = f2bf_fast(Om[t][r] * invl);
    }
    union { uint2 u[2]; bf16x8 v; } aA0, aA1;
    aA0.u[0] = *(const uint2*)&sPw[l16 * LDPP + quad * 8];
    aA0.u[1] = *(const uint2*)&sPw[l16 * LDPP + quad * 8 + 4];
    aA1.u[0] = *(const uint2*)&sPw[l16 * LDPP + 32 + quad * 8];
    aA1.u[1] = *(const uint2*)&sPw[l16 * LDPP + 32 + quad * 8 + 4];

    // out = relu(av @ W^T + res) for this wave's strip (rows wv*16 + half*64)
    const u16* sW = smem + WOFF;
    f32x4 R[4];
#pragma unroll
    for (int t = 0; t < 4; t++) {
        bf16x8 b0 = *(const bf16x8*)&sW[(l16 + 16 * t) * LDP + quad * 8];
        bf16x8 b1 = *(const bf16x8*)&sW[(l16 + 16 * t) * LDP + 32 + quad * 8];
        R[t] = __builtin_amdgcn_mfma_f32_16x16x32_bf16(aA1.v, b1,
               __builtin_amdgcn_mfma_f32_16x16x32_bf16(aA0.v, b0, fzero, 0, 0, 0), 0, 0, 0);
    }
#pragma unroll
    for (int t = 0; t < 4; t++) {
#pragma unroll
        for (int r = 0; r < 4; r++) {
            int row = qt * BM + wv * 16 + half * 64 + quad * 4 + r;
            int col = l16 + 16 * t;
            size_t idx = ((size_t)bh * NSEQ + row) * DIM + col;
            float rv = res_isf ? ((const float*)res)[idx] : bf2f(((const u16*)res)[idx]);
            float v = R[t][r] + rv;
            v = (v < 0.f) ? 0.f : v;       // NaN-transparent relu
            if (out_isf) ((float*)outp)[idx] = v;
            else         ((u16*)outp)[idx]  = f2bf(v);
        }
    }
}

extern "C" void kernel_launch(void* const* d_in, const int* in_sizes, int n_in,
                              void* d_out, int out_size, void* d_ws, size_t ws_size,
                              hipStream_t stream) {
    const float* x  = (const float*)d_in[0];
    const float* W1 = (const float*)d_in[1];
    const float* W2 = (const float*)d_in[2];
    const float* a1 = (const float*)d_in[3];
    const float* a2 = (const float*)d_in[4];
    float* outp = (float*)d_out;

    size_t elems = (size_t)BH * NSEQ * DIM;        // 4,194,304
    u16* xn = (u16*)d_ws;                          // 8.39 MB
    u16* xT = xn + elems;                          // 8.39 MB
    u16* y1 = xT + elems;                          // 8.39 MB (layer-1 out, bf16)

    dim3 pgrid(BH * 16),     pblk(256);
    dim3 agrid(BH * QTILES), ablk(512);            // 512 blocks x 8 waves = 16 waves/CU

    // layer 1: x (fp32) -> y1 (bf16)
    ContentGCN_5059471475267_prep<<<pgrid, pblk, 0, stream>>>(x, 1, xn, xT);
    ContentGCN_5059471475267_attn<<<agrid, ablk, 0, stream>>>(xn, xT, x, 1, W1, a1, y1, 0);
    // layer 2: y1 (bf16) -> d_out (fp32)
    ContentGCN_5059471475267_prep<<<pgrid, pblk, 0, stream>>>(y1, 0, xn, xT);
    ContentGCN_5059471475267_attn<<<agrid, ablk, 0, stream>>>(xn, xT, y1, 0, W2, a2, outp, 1);
}